// Round 1
// baseline (43.535 us; speedup 1.0000x reference)
//
#include <hip/hip_runtime.h>
#include <hip/hip_bf16.h>

#define NPTS 1024
#define HID 128
#define KNN 10
#define FLT_MAX_ 3.402823466e+38f

// ---------------------------------------------------------------------------
// Kernel A: build lookup tables.
//   T_d[v][c] = sinusoid(v) . Wd[c][:]   for v in [0,256)
//   T_a[v][c] = sinusoid(v) . Wa[c][:]   for v in [0,16)
// sinusoid(v)[2m]   = sin(v * dt[m])
// sinusoid(v)[2m+1] = cos(v * dt[m]),  dt[m] = exp(-m * ln(10000)/64)
// grid: 272 blocks (256 for T_d, 16 for T_a), 128 threads each.
// ---------------------------------------------------------------------------
__global__ __launch_bounds__(128) void gse_build_tables(
    const float* __restrict__ Wd, const float* __restrict__ Wa,
    float* __restrict__ Td, float* __restrict__ Ta) {
    __shared__ float S[HID];
    const int blk = blockIdx.x;
    const int t = threadIdx.x;          // 0..127
    const bool isA = (blk >= 256);
    const int v = isA ? (blk - 256) : blk;

    // thread t computes sinusoid channel t of value v
    {
        const int m = t >> 1;
        const float dtm = expf((float)m * (float)(-9.210340371976184 / 64.0));
        const float arg = (float)v * dtm;
        S[t] = (t & 1) ? cosf(arg) : sinf(arg);
    }
    __syncthreads();

    const float* W = isA ? Wa : Wd;
    float acc = 0.0f;
    const float* wrow = W + t * HID;    // out channel c = t: dot with row c of W
    #pragma unroll 8
    for (int h = 0; h < HID; ++h) acc += S[h] * wrow[h];

    float* T = isA ? Ta : Td;
    T[v * HID + t] = acc;
}

// ---------------------------------------------------------------------------
// Kernel B: per-point main kernel. One block (256 threads) per point.
//   phase 1: 1024 distances -> LDS dist[] + 256-bin histogram
//   phase 2: iterated argmin x10 (tie-break: lower index, matching lax.top_k)
//   phase 3: 10 unit vectors
//   phase 4: 100 pairwise angles -> presence bitmask over bins [0,12]
//   phase 5: per-channel: histogram dot T_d + masked max over T_a
// ---------------------------------------------------------------------------
__global__ __launch_bounds__(256) void gse_main(
    const float* __restrict__ pts,      // (B, 1024, 3)
    const float* __restrict__ bd,
    const float* __restrict__ ba,
    const float* __restrict__ Td,       // (256, 128)
    const float* __restrict__ Ta,       // (16, 128)
    float* __restrict__ out) {          // (B, 1024, 128)
    const int gid = blockIdx.x;         // b*1024 + i
    const int b = gid >> 10;
    const int i = gid & 1023;
    const float* P = pts + (size_t)b * NPTS * 3;
    const int t = threadIdx.x;

    __shared__ float dist[NPTS];
    __shared__ int   hist[256];
    __shared__ float rv[256];
    __shared__ int   ri[256];
    __shared__ int   nn[KNN];
    __shared__ float ux[KNN], uy[KNN], uz[KNN];
    __shared__ unsigned amask;

    hist[t] = 0;
    if (t == 0) amask = 0u;

    const float px = P[i * 3 + 0];
    const float py = P[i * 3 + 1];
    const float pz = P[i * 3 + 2];
    __syncthreads();

    // phase 1: distances + histogram
    for (int j = t; j < NPTS; j += 256) {
        const float dx = px - P[j * 3 + 0];
        const float dy = py - P[j * 3 + 1];
        const float dz = pz - P[j * 3 + 2];
        const float d = sqrtf(dx * dx + dy * dy + dz * dz);
        dist[j] = d;
        float q = rintf(d / 0.2f);                 // jnp.round = half-to-even
        q = fminf(fmaxf(q, 0.0f), 255.0f);
        atomicAdd(&hist[(int)q], 1);
    }
    __syncthreads();

    // phase 2: top-10 nearest (smallest dist, ties -> lower index)
    for (int r = 0; r < KNN; ++r) {
        float bv = FLT_MAX_;
        int bi = 0x7fffffff;
        for (int j = t; j < NPTS; j += 256) {
            const float vdl = dist[j];
            if (vdl < bv || (vdl == bv && j < bi)) { bv = vdl; bi = j; }
        }
        rv[t] = bv; ri[t] = bi;
        __syncthreads();
        for (int s = 128; s > 0; s >>= 1) {
            if (t < s) {
                const float ov = rv[t + s];
                const int oi = ri[t + s];
                if (ov < rv[t] || (ov == rv[t] && oi < ri[t])) { rv[t] = ov; ri[t] = oi; }
            }
            __syncthreads();
        }
        if (t == 0) { nn[r] = ri[0]; dist[ri[0]] = FLT_MAX_; }
        __syncthreads();
    }

    // phase 3: unit vectors to the 10 neighbours
    if (t < KNN) {
        const int j = nn[t];
        const float vx = P[j * 3 + 0] - px;
        const float vy = P[j * 3 + 1] - py;
        const float vz = P[j * 3 + 2] - pz;
        const float nrm = sqrtf(vx * vx + vy * vy + vz * vz);
        const float den = nrm + 1e-8f;
        ux[t] = vx / den; uy[t] = vy / den; uz[t] = vz / den;
    }
    __syncthreads();

    // phase 4: 100 pairwise angles -> presence mask
    if (t < KNN * KNN) {
        const int k = t / KNN, l = t % KNN;
        float c = ux[k] * ux[l] + uy[k] * uy[l] + uz[k] * uz[l];
        c = fminf(fmaxf(c, -1.0f), 1.0f);
        const float ang = acosf(c);
        float q = rintf(ang * (float)(180.0 / (15.0 * M_PI)));
        q = fminf(fmaxf(q, 0.0f), 15.0f);          // bins 0..12 possible; clamp for safety
        atomicOr(&amask, 1u << (int)q);
    }
    __syncthreads();

    // phase 5: per-channel output
    if (t < HID) {
        const int c = t;
        float sd = 0.0f;
        #pragma unroll 8
        for (int v = 0; v < 256; ++v) sd += (float)hist[v] * Td[v * HID + c];
        float ma = -FLT_MAX_;
        unsigned m = amask;
        while (m) {
            const int v = __ffs(m) - 1;
            m &= m - 1;
            ma = fmaxf(ma, Ta[v * HID + c]);
        }
        out[(size_t)gid * HID + c] = sd * (1.0f / (float)NPTS) + bd[c] + ma + ba[c];
    }
}

extern "C" void kernel_launch(void* const* d_in, const int* in_sizes, int n_in,
                              void* d_out, int out_size, void* d_ws, size_t ws_size,
                              hipStream_t stream) {
    const float* pts = (const float*)d_in[0];
    const float* Wd  = (const float*)d_in[1];
    const float* bd  = (const float*)d_in[2];
    const float* Wa  = (const float*)d_in[3];
    const float* ba  = (const float*)d_in[4];
    float* out = (float*)d_out;

    const int B = in_sizes[0] / (NPTS * 3);

    float* Td = (float*)d_ws;                        // 256*128*4 = 128 KiB
    float* Ta = Td + 256 * HID;                      // 16*128*4  =   8 KiB

    gse_build_tables<<<272, 128, 0, stream>>>(Wd, Wa, Td, Ta);
    gse_main<<<B * NPTS, 256, 0, stream>>>(pts, bd, ba, Td, Ta, out);
}

// Round 2
// 39.894 us; speedup vs baseline: 1.0913x; 1.0913x over previous
//
#include <hip/hip_runtime.h>
#include <hip/hip_bf16.h>

#define NPTS 1024
#define HID 128
#define KNN 10
#define FLT_MAX_ 3.402823466e+38f

// ---------------------------------------------------------------------------
// Kernel A: build lookup tables (with epilogue terms folded in).
//   Td[v][c] = (sinusoid(v) . Wd[c][:] + bd[c]) / 1024     v in [0,256)
//   Ta[v][c] =  sinusoid(v) . Wa[c][:] + ba[c]             v in [0,16)
// Folding is valid because sum(hist) == 1024 exactly and max(x+ba)=max(x)+ba.
// grid: 272 blocks (256 for Td, 16 for Ta), 128 threads each.
// ---------------------------------------------------------------------------
__global__ __launch_bounds__(128) void gse_build_tables(
    const float* __restrict__ Wd, const float* __restrict__ bd,
    const float* __restrict__ Wa, const float* __restrict__ ba,
    float* __restrict__ Td, float* __restrict__ Ta) {
    __shared__ float S[HID];
    const int blk = blockIdx.x;
    const int t = threadIdx.x;          // 0..127
    const bool isA = (blk >= 256);
    const int v = isA ? (blk - 256) : blk;

    {
        const int m = t >> 1;
        const float dtm = expf((float)m * (float)(-9.210340371976184 / 64.0));
        const float arg = (float)v * dtm;
        S[t] = (t & 1) ? cosf(arg) : sinf(arg);
    }
    __syncthreads();

    const float* W = isA ? Wa : Wd;
    float acc = 0.0f;
    const float* wrow = W + t * HID;
    #pragma unroll 8
    for (int h = 0; h < HID; ++h) acc += S[h] * wrow[h];

    if (isA) {
        Ta[v * HID + t] = acc + ba[t];
    } else {
        Td[v * HID + t] = (acc + bd[t]) * (1.0f / (float)NPTS);
    }
}

// ---------------------------------------------------------------------------
// Kernel B: ONE WAVE PER POINT (block = 64, grid = B*1024).
//   phase 1: 16 dists/lane in registers + LDS histogram
//   phase 2: top-10 via 10 x (16 masked reg-compares + 6-step shfl_xor
//            lexicographic argmin) -- no barriers, no LDS
//   phase 3: 10 unit vectors -> LDS
//   phase 4: 100 pairwise angles -> presence bitmask (bins 0..12)
//   phase 5: compact nonzero hist bins, then per-channel LUT dot + masked max
// ---------------------------------------------------------------------------
__global__ __launch_bounds__(64) void gse_main(
    const float* __restrict__ pts,      // (B, 1024, 3)
    const float* __restrict__ Td,       // (256, 128), bd/1024 folded
    const float* __restrict__ Ta,       // (16, 128), ba folded
    float* __restrict__ out) {          // (B, 1024, 128)
    const int gid = blockIdx.x;         // b*1024 + i
    const int b = gid >> 10;
    const int i = gid & 1023;
    const float* P = pts + (size_t)b * NPTS * 3;
    const int lane = threadIdx.x;       // 0..63

    __shared__ int      hist[256];
    __shared__ int      cbins[256];
    __shared__ int      ccnts[256];
    __shared__ float    uxs[16], uys[16], uzs[16];
    __shared__ unsigned amask;
    __shared__ int      cnt;

    #pragma unroll
    for (int v = 0; v < 4; ++v) hist[lane + v * 64] = 0;
    if (lane == 0) { amask = 0u; cnt = 0; }

    const float px = P[i * 3 + 0];
    const float py = P[i * 3 + 1];
    const float pz = P[i * 3 + 2];
    __syncthreads();                    // single wave: cheap s_barrier

    // ---- phase 1: distances (registers) + histogram (LDS atomics) ----
    float d[16];
    #pragma unroll
    for (int s = 0; s < 16; ++s) {
        const int j = s * 64 + lane;
        const float dx = px - P[j * 3 + 0];
        const float dy = py - P[j * 3 + 1];
        const float dz = pz - P[j * 3 + 2];
        const float dd = sqrtf(dx * dx + dy * dy + dz * dz);
        d[s] = dd;
        float q = rintf(dd / 0.2f);     // matches jnp.round (half-to-even)
        q = fminf(fmaxf(q, 0.0f), 255.0f);
        atomicAdd(&hist[(int)q], 1);
    }

    // ---- phase 2: top-10 (smallest dist, ties -> lower index) ----
    unsigned valid = 0xffffu;
    float nvx = 0.f, nvy = 0.f, nvz = 0.f;   // neighbour coords for MY rank
    #pragma unroll
    for (int r = 0; r < KNN; ++r) {
        float bv = FLT_MAX_;
        int bi = 0x7fffffff;
        #pragma unroll
        for (int s = 0; s < 16; ++s) {
            if (valid & (1u << s)) {
                const float v_ = d[s];
                const int id_ = s * 64 + lane;
                if (v_ < bv || (v_ == bv && id_ < bi)) { bv = v_; bi = id_; }
            }
        }
        #pragma unroll
        for (int off = 32; off > 0; off >>= 1) {
            const float ov = __shfl_xor(bv, off);
            const int oi = __shfl_xor(bi, off);
            if (ov < bv || (ov == bv && oi < bi)) { bv = ov; bi = oi; }
        }
        // all lanes now hold the global argmin (bv, bi)
        if (lane == (bi & 63)) valid &= ~(1u << (bi >> 6));  // owner removes it
        if (lane == r) {                 // lane r owns neighbour rank r
            nvx = P[bi * 3 + 0];
            nvy = P[bi * 3 + 1];
            nvz = P[bi * 3 + 2];
        }
    }

    // ---- phase 3: unit vectors ----
    if (lane < KNN) {
        const float vx = nvx - px;
        const float vy = nvy - py;
        const float vz = nvz - pz;
        const float nrm = sqrtf(vx * vx + vy * vy + vz * vz);
        const float den = nrm + 1e-8f;
        uxs[lane] = vx / den; uys[lane] = vy / den; uzs[lane] = vz / den;
    }
    __syncthreads();

    // ---- phase 4: 100 pairwise angles -> presence mask ----
    for (int t = lane; t < KNN * KNN; t += 64) {
        const int k = t / KNN, l = t % KNN;
        float c = uxs[k] * uxs[l] + uys[k] * uys[l] + uzs[k] * uzs[l];
        c = fminf(fmaxf(c, -1.0f), 1.0f);
        const float ang = acosf(c);
        float q = rintf(ang * (float)(180.0 / (15.0 * M_PI)));
        q = fminf(fmaxf(q, 0.0f), 15.0f);
        atomicOr(&amask, 1u << (int)q);
    }

    // ---- compact nonzero histogram bins ----
    __syncthreads();
    #pragma unroll
    for (int s = 0; s < 4; ++s) {
        const int v = s * 64 + lane;
        const int h = hist[v];
        if (h) {
            const int p = atomicAdd(&cnt, 1);
            cbins[p] = v;
            ccnts[p] = h;
        }
    }
    __syncthreads();

    // ---- phase 5: per-channel output (2 channels per lane) ----
    const int n = cnt;
    float s0 = 0.0f, s1 = 0.0f;
    for (int p = 0; p < n; ++p) {
        const int v = cbins[p];
        const float h = (float)ccnts[p];
        const float* row = Td + v * HID;
        s0 += h * row[lane];
        s1 += h * row[lane + 64];
    }
    float m0 = -FLT_MAX_, m1 = -FLT_MAX_;
    unsigned m = amask;
    while (m) {
        const int v = __ffs(m) - 1;
        m &= m - 1;
        m0 = fmaxf(m0, Ta[v * HID + lane]);
        m1 = fmaxf(m1, Ta[v * HID + lane + 64]);
    }
    float* o = out + (size_t)gid * HID;
    o[lane]      = s0 + m0;
    o[lane + 64] = s1 + m1;
}

extern "C" void kernel_launch(void* const* d_in, const int* in_sizes, int n_in,
                              void* d_out, int out_size, void* d_ws, size_t ws_size,
                              hipStream_t stream) {
    const float* pts = (const float*)d_in[0];
    const float* Wd  = (const float*)d_in[1];
    const float* bd  = (const float*)d_in[2];
    const float* Wa  = (const float*)d_in[3];
    const float* ba  = (const float*)d_in[4];
    float* out = (float*)d_out;

    const int B = in_sizes[0] / (NPTS * 3);

    float* Td = (float*)d_ws;                        // 256*128*4 = 128 KiB
    float* Ta = Td + 256 * HID;                      // 16*128*4  =   8 KiB

    gse_build_tables<<<272, 128, 0, stream>>>(Wd, bd, Wa, ba, Td, Ta);
    gse_main<<<B * NPTS, 64, 0, stream>>>(pts, Td, Ta, out);
}

// Round 3
// 25.193 us; speedup vs baseline: 1.7280x; 1.5835x over previous
//
#include <hip/hip_runtime.h>
#include <hip/hip_bf16.h>

#define NPTS 1024
#define HID 128
#define KNN 10
#define FLT_MAX_ 3.402823466e+38f

// ---------------------------------------------------------------------------
// Kernel A: build LUTs (epilogue folded).
//   Td[v][c] = (sinusoid(v).Wd[c] + bd[c]) / 1024,  v in [0,256)
//   Ta[v][c] =  sinusoid(v).Wa[c] + ba[c],          v in [0,16)
// 272 blocks x 512 threads; 4-way split dot + LDS reduce (deterministic order).
// ---------------------------------------------------------------------------
__global__ __launch_bounds__(512) void gse_build_tables(
    const float* __restrict__ Wd, const float* __restrict__ bd,
    const float* __restrict__ Wa, const float* __restrict__ ba,
    float* __restrict__ Td, float* __restrict__ Ta) {
    __shared__ float S[HID];
    __shared__ float part[512];
    const int blk = blockIdx.x;
    const bool isA = (blk >= 256);
    const int v = isA ? blk - 256 : blk;
    const int tid = threadIdx.x;
    const int c = tid & 127;
    const int seg = tid >> 7;              // 0..3

    if (tid < HID) {
        const int m = tid >> 1;
        const float dtm = expf((float)m * (float)(-9.210340371976184 / 64.0));
        const float arg = (float)v * dtm;
        S[tid] = (tid & 1) ? cosf(arg) : sinf(arg);
    }
    __syncthreads();

    const float* W = isA ? Wa : Wd;
    const float* wrow = W + c * HID + seg * 32;
    const float* srow = S + seg * 32;
    float acc = 0.0f;
    #pragma unroll
    for (int h = 0; h < 32; h += 4) {
        const float4 wv = *reinterpret_cast<const float4*>(wrow + h);
        acc += srow[h] * wv.x + srow[h + 1] * wv.y + srow[h + 2] * wv.z + srow[h + 3] * wv.w;
    }
    part[tid] = acc;
    __syncthreads();

    if (tid < HID) {
        const float s = (part[c] + part[c + 128]) + (part[c + 256] + part[c + 384]);
        if (isA) Ta[v * HID + c] = s + ba[c];
        else     Td[v * HID + c] = (s + bd[c]) * (1.0f / (float)NPTS);
    }
}

// ---------------------------------------------------------------------------
// Kernel B: one point per block, 2 waves (block=128).
//   stage points -> LDS; 8 dists/lane (regs) + LDS hist;
//   top-10 via histogram-pruned rank selection (fallback: serial per-wave);
//   angles -> bitmask; per-channel LUT dot (hist order, deterministic) + max.
// ---------------------------------------------------------------------------
__global__ __launch_bounds__(128, 4) void gse_main(
    const float* __restrict__ pts,      // (B, 1024, 3)
    const float* __restrict__ Td,       // (256, 128)
    const float* __restrict__ Ta,       // (16, 128)
    float* __restrict__ out) {          // (B, 1024, 128)
    const int gid = blockIdx.x;
    const int b = gid >> 10;
    const int i = gid & 1023;
    const float* P = pts + (size_t)b * NPTS * 3;
    const int tid = threadIdx.x;        // 0..127
    const int lane = tid & 63;
    const int w = tid >> 6;             // wave 0/1

    __shared__ float Px[NPTS], Py[NPTS], Pz[NPTS];
    __shared__ int hist[256];
    __shared__ float cd[64];
    __shared__ int cidx[64];
    __shared__ int nn[KNN];
    __shared__ float uxs[KNN], uys[KNN], uzs[KNN];
    __shared__ unsigned amask_s;
    __shared__ int ccnt;

    hist[tid] = 0;
    hist[tid + 128] = 0;
    if (tid == 0) { amask_s = 0u; ccnt = 0; }

    const float px = P[i * 3 + 0];
    const float py = P[i * 3 + 1];
    const float pz = P[i * 3 + 2];

    // ---- stage points into LDS (SoA) ----
    const float4* Pv = reinterpret_cast<const float4*>(P);
    #pragma unroll
    for (int k = 0; k < 6; ++k) {
        const int it = tid + k * 128;
        const float4 f = Pv[it];
        const int base = it * 4;
        float vals[4] = {f.x, f.y, f.z, f.w};
        #pragma unroll
        for (int e = 0; e < 4; ++e) {
            const int idx = base + e;
            const int j = idx / 3;
            const int r = idx - 3 * j;
            float* dst = (r == 0) ? Px : (r == 1) ? Py : Pz;
            dst[j] = vals[e];
        }
    }
    __syncthreads();

    // ---- phase 1: 8 distances/lane + histogram ----
    float d8[8];
    int q8[8];
    const int jb = w * 512;
    #pragma unroll
    for (int s = 0; s < 8; ++s) {
        const int j = jb + s * 64 + lane;
        const float dx = px - Px[j];
        const float dy = py - Py[j];
        const float dz = pz - Pz[j];
        const float dd = sqrtf(dx * dx + dy * dy + dz * dz);
        d8[s] = dd;
        float q = rintf(dd / 0.2f);
        q = fminf(fmaxf(q, 0.0f), 255.0f);
        const int qi = (int)q;
        q8[s] = qi;
        atomicAdd(&hist[qi], 1);
    }
    __syncthreads();

    // ---- scan bins 0..63 for b10; maxbin via ballots (both waves redundant) ----
    int cum = hist[lane];
    #pragma unroll
    for (int off = 1; off < 64; off <<= 1) {
        const int n_ = __shfl_up(cum, off);
        if (lane >= off) cum += n_;
    }
    const unsigned long long bal = __ballot(cum >= KNN);
    const unsigned long long nz0 = __ballot(hist[lane] != 0);
    const unsigned long long nz1 = __ballot(hist[64 + lane] != 0);
    const unsigned long long nz2 = __ballot(hist[128 + lane] != 0);
    const unsigned long long nz3 = __ballot(hist[192 + lane] != 0);
    int maxbin;
    if (nz3)      maxbin = 192 + 63 - __clzll((long long)nz3);
    else if (nz2) maxbin = 128 + 63 - __clzll((long long)nz2);
    else if (nz1) maxbin = 64 + 63 - __clzll((long long)nz1);
    else          maxbin = 63 - __clzll((long long)nz0);

    int b10 = 0, c = 0;
    if (bal) { b10 = __ffsll(bal) - 1; c = __shfl(cum, b10); }
    const bool fast = (bal != 0ull) && (c <= 64);

    if (fast) {
        // candidates = all points with bin <= b10 (provably contains top-10;
        // count == c <= 64 so no overflow possible)
        #pragma unroll
        for (int s = 0; s < 8; ++s) {
            if (q8[s] <= b10) {
                const int p = atomicAdd(&ccnt, 1);
                cd[p] = d8[s];
                cidx[p] = jb + s * 64 + lane;
            }
        }
        __syncthreads();
        if (tid < c) {
            const float md = cd[tid];
            const int mi = cidx[tid];
            int rank = 0;
            #pragma unroll 4
            for (int p = 0; p < c; ++p) {
                const float od = cd[p];
                const int oi = cidx[p];
                rank += (od < md || (od == md && oi < mi)) ? 1 : 0;
            }
            if (rank < KNN) nn[rank] = mi;
        }
        __syncthreads();
    } else {
        // fallback: per-wave serial top-10 over regs, then 20-way rank merge
        unsigned valid = 0xffu;
        float keep_d = 0.0f;
        int keep_i = 0;
        for (int r = 0; r < KNN; ++r) {
            float bv = FLT_MAX_;
            int bi = 0x7fffffff;
            #pragma unroll
            for (int s = 0; s < 8; ++s) {
                if (valid & (1u << s)) {
                    const float v_ = d8[s];
                    const int id_ = jb + s * 64 + lane;
                    if (v_ < bv || (v_ == bv && id_ < bi)) { bv = v_; bi = id_; }
                }
            }
            #pragma unroll
            for (int off = 32; off > 0; off >>= 1) {
                const float ov = __shfl_xor(bv, off);
                const int oi = __shfl_xor(bi, off);
                if (ov < bv || (ov == bv && oi < bi)) { bv = ov; bi = oi; }
            }
            const int loc = bi - jb;
            if (loc >= 0 && loc < 512 && lane == (loc & 63)) valid &= ~(1u << (loc >> 6));
            if (lane == r) { keep_d = bv; keep_i = bi; }
        }
        if (lane < KNN) { cd[w * KNN + lane] = keep_d; cidx[w * KNN + lane] = keep_i; }
        __syncthreads();
        if (tid < 2 * KNN) {
            const float md = cd[tid];
            const int mi = cidx[tid];
            int rank = 0;
            for (int p = 0; p < 2 * KNN; ++p) {
                const float od = cd[p];
                const int oi = cidx[p];
                rank += (od < md || (od == md && oi < mi)) ? 1 : 0;
            }
            if (rank < KNN) nn[rank] = mi;
        }
        __syncthreads();
    }

    // ---- phase 3: unit vectors ----
    if (tid < KNN) {
        const int j = nn[tid];
        const float vx = Px[j] - px;
        const float vy = Py[j] - py;
        const float vz = Pz[j] - pz;
        const float nrm = sqrtf(vx * vx + vy * vy + vz * vz);
        const float den = nrm + 1e-8f;
        uxs[tid] = vx / den; uys[tid] = vy / den; uzs[tid] = vz / den;
    }
    __syncthreads();

    // ---- phase 4: 100 pairwise angles -> presence mask ----
    if (tid < KNN * KNN) {
        const int k = tid / KNN, l = tid % KNN;
        float cc = uxs[k] * uxs[l] + uys[k] * uys[l] + uzs[k] * uzs[l];
        cc = fminf(fmaxf(cc, -1.0f), 1.0f);
        const float ang = acosf(cc);
        float q = rintf(ang * (float)(180.0 / (15.0 * M_PI)));
        q = fminf(fmaxf(q, 0.0f), 15.0f);
        atomicOr(&amask_s, 1u << (int)q);
    }
    __syncthreads();

    // ---- phase 5: per-channel (1 channel/thread) ----
    const unsigned am = amask_s;
    float s = 0.0f;
    const float* tdc = Td + tid;
    #pragma unroll 4
    for (int v = 0; v <= maxbin; ++v) {
        s += (float)hist[v] * tdc[v * HID];     // zero bins add exact 0.0f
    }
    float mx = -FLT_MAX_;
    const float* tac = Ta + tid;
    #pragma unroll
    for (int v = 0; v < 16; ++v) {              // independent loads, masked fmax
        const float tv = tac[v * HID];
        if (am & (1u << v)) mx = fmaxf(mx, tv);
    }
    out[(size_t)gid * HID + tid] = s + mx;
}

extern "C" void kernel_launch(void* const* d_in, const int* in_sizes, int n_in,
                              void* d_out, int out_size, void* d_ws, size_t ws_size,
                              hipStream_t stream) {
    const float* pts = (const float*)d_in[0];
    const float* Wd  = (const float*)d_in[1];
    const float* bd  = (const float*)d_in[2];
    const float* Wa  = (const float*)d_in[3];
    const float* ba  = (const float*)d_in[4];
    float* out = (float*)d_out;

    const int B = in_sizes[0] / (NPTS * 3);

    float* Td = (float*)d_ws;                        // 256*128*4 = 128 KiB
    float* Ta = Td + 256 * HID;                      // 16*128*4  =   8 KiB

    gse_build_tables<<<272, 512, 0, stream>>>(Wd, bd, Wa, ba, Td, Ta);
    gse_main<<<B * NPTS, 128, 0, stream>>>(pts, Td, Ta, out);
}

// Round 4
// 23.373 us; speedup vs baseline: 1.8626x; 1.0779x over previous
//
#include <hip/hip_runtime.h>
#include <hip/hip_bf16.h>

#define NPTS 1024
#define HID 128
#define KNN 10
#define FLT_MAX_ 3.402823466e+38f

// ---------------------------------------------------------------------------
// Kernel A: build LUTs (epilogue folded) + repack points to float4 SoA-ish.
//   Td[v][c] = (sinusoid(v).Wd[c] + bd[c]) / 1024,  v in [0,256)
//   Ta[v][c] =  sinusoid(v).Wa[c] + ba[c],          v in [0,16)
//   P4[j]    = (x,y,z,0) for each point            (blocks >= 272)
// grid: 272 + ceil(nP/512) blocks x 512 threads.
// ---------------------------------------------------------------------------
__global__ __launch_bounds__(512) void gse_build_tables(
    const float* __restrict__ Wd, const float* __restrict__ bd,
    const float* __restrict__ Wa, const float* __restrict__ ba,
    const float* __restrict__ pts, int nP,
    float* __restrict__ Td, float* __restrict__ Ta, float4* __restrict__ P4) {
    const int blk = blockIdx.x;
    const int tid = threadIdx.x;

    if (blk >= 272) {                       // point repack blocks
        const int idx = (blk - 272) * 512 + tid;
        if (idx < nP) {
            P4[idx] = make_float4(pts[idx * 3 + 0], pts[idx * 3 + 1],
                                  pts[idx * 3 + 2], 0.0f);
        }
        return;
    }

    __shared__ float S[HID];
    __shared__ float part[512];
    const bool isA = (blk >= 256);
    const int v = isA ? blk - 256 : blk;
    const int c = tid & 127;
    const int seg = tid >> 7;               // 0..3

    if (tid < HID) {
        const int m = tid >> 1;
        const float dtm = expf((float)m * (float)(-9.210340371976184 / 64.0));
        const float arg = (float)v * dtm;
        S[tid] = (tid & 1) ? cosf(arg) : sinf(arg);
    }
    __syncthreads();

    const float* W = isA ? Wa : Wd;
    const float* wrow = W + c * HID + seg * 32;
    const float* srow = S + seg * 32;
    float acc = 0.0f;
    #pragma unroll
    for (int h = 0; h < 32; h += 4) {
        const float4 wv = *reinterpret_cast<const float4*>(wrow + h);
        acc += srow[h] * wv.x + srow[h + 1] * wv.y + srow[h + 2] * wv.z + srow[h + 3] * wv.w;
    }
    part[tid] = acc;
    __syncthreads();

    if (tid < HID) {
        const float s = (part[c] + part[c + 128]) + (part[c + 256] + part[c + 384]);
        if (isA) Ta[v * HID + c] = s + ba[c];
        else     Td[v * HID + c] = (s + bd[c]) * (1.0f / (float)NPTS);
    }
}

// ---------------------------------------------------------------------------
// Kernel B: one point per block, 4 waves (block=256), no point staging.
//   phase 1: 4 dists/lane from L1-cached float4 + per-wave private hists
//   hist merge; histogram-pruned rank top-10 (fallback: 4x wave top-10 merge)
//   angles -> bitmask; phase 5 split even/odd bins across half-blocks.
// ---------------------------------------------------------------------------
__global__ __launch_bounds__(256, 8) void gse_main(
    const float4* __restrict__ P4,      // (B*1024)
    const float* __restrict__ Td,       // (256, 128)
    const float* __restrict__ Ta,       // (16, 128)
    float* __restrict__ out) {          // (B, 1024, 128)
    const int gid = blockIdx.x;
    const int b = gid >> 10;
    const int i = gid & 1023;
    const float4* P = P4 + (size_t)b * NPTS;
    const int tid = threadIdx.x;        // 0..255
    const int lane = tid & 63;
    const int w = tid >> 6;             // wave 0..3

    __shared__ int h4[4][256];
    __shared__ float cd[64];
    __shared__ int cidx[64];
    __shared__ int nn[KNN];
    __shared__ float uxs[KNN], uys[KNN], uzs[KNN];
    __shared__ float sums[256], mxs[256];
    __shared__ unsigned amask_s;
    __shared__ int ccnt;

    {
        int* hf = (int*)h4;
        hf[tid] = 0; hf[tid + 256] = 0; hf[tid + 512] = 0; hf[tid + 768] = 0;
    }
    if (tid == 0) { amask_s = 0u; ccnt = 0; }
    const float4 p = P[i];
    __syncthreads();

    // ---- phase 1: 4 distances/lane + private per-wave hist ----
    float d4[4];
    int q4[4];
    const int jb = w * 256;
    #pragma unroll
    for (int s = 0; s < 4; ++s) {
        const int j = jb + s * 64 + lane;
        const float4 q = P[j];
        const float dx = p.x - q.x;
        const float dy = p.y - q.y;
        const float dz = p.z - q.z;
        const float dd = sqrtf(dx * dx + dy * dy + dz * dz);
        d4[s] = dd;
        float qq = rintf(dd / 0.2f);    // matches jnp.round (half-to-even)
        qq = fminf(fmaxf(qq, 0.0f), 255.0f);
        q4[s] = (int)qq;
        atomicAdd(&h4[w][q4[s]], 1);
    }
    __syncthreads();

    // ---- merge hists (bin = tid) ----
    const int hsum = h4[0][tid] + h4[1][tid] + h4[2][tid] + h4[3][tid];
    h4[0][tid] = hsum;
    __syncthreads();
    const int* hist = h4[0];

    // ---- scan bins 0..63 for b10; maxbin via ballots (per-wave redundant) ----
    int cum = hist[lane];
    #pragma unroll
    for (int off = 1; off < 64; off <<= 1) {
        const int n_ = __shfl_up(cum, off);
        if (lane >= off) cum += n_;
    }
    const unsigned long long bal = __ballot(cum >= KNN);
    const unsigned long long nz0 = __ballot(hist[lane] != 0);
    const unsigned long long nz1 = __ballot(hist[64 + lane] != 0);
    const unsigned long long nz2 = __ballot(hist[128 + lane] != 0);
    const unsigned long long nz3 = __ballot(hist[192 + lane] != 0);
    int maxbin;
    if (nz3)      maxbin = 192 + 63 - __clzll((long long)nz3);
    else if (nz2) maxbin = 128 + 63 - __clzll((long long)nz2);
    else if (nz1) maxbin = 64 + 63 - __clzll((long long)nz1);
    else          maxbin = 63 - __clzll((long long)nz0);

    int b10 = 0, c = 0;
    if (bal) { b10 = __ffsll(bal) - 1; c = __shfl(cum, b10); }
    const bool fast = (bal != 0ull) && (c <= 64);   // block-uniform

    if (fast) {
        // candidates = all points with bin <= b10 (superset of top-10, c <= 64)
        #pragma unroll
        for (int s = 0; s < 4; ++s) {
            if (q4[s] <= b10) {
                const int pp = atomicAdd(&ccnt, 1);
                cd[pp] = d4[s];
                cidx[pp] = jb + s * 64 + lane;
            }
        }
        __syncthreads();
        if (tid < c) {
            const float md = cd[tid];
            const int mi = cidx[tid];
            int rank = 0;
            #pragma unroll 4
            for (int pp = 0; pp < c; ++pp) {
                const float od = cd[pp];
                const int oi = cidx[pp];
                rank += (od < md || (od == md && oi < mi)) ? 1 : 0;
            }
            if (rank < KNN) nn[rank] = mi;
        }
        __syncthreads();
    } else {
        // fallback: each wave top-10 of its 256 points, then 40-way rank merge
        unsigned valid = 0xfu;
        float keep_d = 0.0f;
        int keep_i = 0;
        for (int r = 0; r < KNN; ++r) {
            float bv = FLT_MAX_;
            int bi = 0x7fffffff;
            #pragma unroll
            for (int s = 0; s < 4; ++s) {
                if (valid & (1u << s)) {
                    const float v_ = d4[s];
                    const int id_ = jb + s * 64 + lane;
                    if (v_ < bv || (v_ == bv && id_ < bi)) { bv = v_; bi = id_; }
                }
            }
            #pragma unroll
            for (int off = 32; off > 0; off >>= 1) {
                const float ov = __shfl_xor(bv, off);
                const int oi = __shfl_xor(bi, off);
                if (ov < bv || (ov == bv && oi < bi)) { bv = ov; bi = oi; }
            }
            const int loc = bi - jb;
            if (loc >= 0 && loc < 256 && lane == (loc & 63)) valid &= ~(1u << (loc >> 6));
            if (lane == r) { keep_d = bv; keep_i = bi; }
        }
        if (lane < KNN) { cd[w * KNN + lane] = keep_d; cidx[w * KNN + lane] = keep_i; }
        __syncthreads();
        if (tid < 4 * KNN) {
            const float md = cd[tid];
            const int mi = cidx[tid];
            int rank = 0;
            for (int pp = 0; pp < 4 * KNN; ++pp) {
                const float od = cd[pp];
                const int oi = cidx[pp];
                rank += (od < md || (od == md && oi < mi)) ? 1 : 0;
            }
            if (rank < KNN) nn[rank] = mi;
        }
        __syncthreads();
    }

    // ---- phase 3: unit vectors ----
    if (tid < KNN) {
        const float4 qn = P[nn[tid]];
        const float vx = qn.x - p.x;
        const float vy = qn.y - p.y;
        const float vz = qn.z - p.z;
        const float nrm = sqrtf(vx * vx + vy * vy + vz * vz);
        const float den = nrm + 1e-8f;
        uxs[tid] = vx / den; uys[tid] = vy / den; uzs[tid] = vz / den;
    }
    __syncthreads();

    // ---- phase 4: 100 pairwise angles -> presence mask ----
    if (tid < KNN * KNN) {
        const int k = tid / KNN, l = tid % KNN;
        float cc = uxs[k] * uxs[l] + uys[k] * uys[l] + uzs[k] * uzs[l];
        cc = fminf(fmaxf(cc, -1.0f), 1.0f);
        const float ang = acosf(cc);
        float q = rintf(ang * (float)(180.0 / (15.0 * M_PI)));
        q = fminf(fmaxf(q, 0.0f), 15.0f);
        atomicOr(&amask_s, 1u << (int)q);
    }
    __syncthreads();

    // ---- phase 5: split even/odd bins + low/high mask across half-blocks ----
    const unsigned am = amask_s;
    const int c7 = tid & 127;
    const int half = tid >> 7;
    float s = 0.0f;
    const float* tdc = Td + c7;
    #pragma unroll 4
    for (int v = half; v <= maxbin; v += 2) {
        s += (float)hist[v] * tdc[v * HID];   // zero bins add exact 0.0f
    }
    float mx = -FLT_MAX_;
    const float* tac = Ta + c7;
    #pragma unroll
    for (int v = 0; v < 8; ++v) {
        const int vv = half * 8 + v;
        const float tv = tac[vv * HID];
        if (am & (1u << vv)) mx = fmaxf(mx, tv);
    }
    sums[tid] = s;
    mxs[tid] = mx;
    __syncthreads();
    if (tid < HID) {
        out[(size_t)gid * HID + tid] =
            (sums[tid] + sums[tid + 128]) + fmaxf(mxs[tid], mxs[tid + 128]);
    }
}

extern "C" void kernel_launch(void* const* d_in, const int* in_sizes, int n_in,
                              void* d_out, int out_size, void* d_ws, size_t ws_size,
                              hipStream_t stream) {
    const float* pts = (const float*)d_in[0];
    const float* Wd  = (const float*)d_in[1];
    const float* bd  = (const float*)d_in[2];
    const float* Wa  = (const float*)d_in[3];
    const float* ba  = (const float*)d_in[4];
    float* out = (float*)d_out;

    const int B = in_sizes[0] / (NPTS * 3);
    const int nP = B * NPTS;

    float* Td = (float*)d_ws;                        // 256*128*4 = 128 KiB
    float* Ta = Td + 256 * HID;                      // 16*128*4  =   8 KiB
    float4* P4 = (float4*)(Ta + 16 * HID);           // nP*16 B

    const int nconv = (nP + 511) / 512;
    gse_build_tables<<<272 + nconv, 512, 0, stream>>>(Wd, bd, Wa, ba, pts, nP, Td, Ta, P4);
    gse_main<<<nP, 256, 0, stream>>>(P4, Td, Ta, out);
}